// Round 1
// 620.715 us; speedup vs baseline: 1.1854x; 1.1854x over previous
//
#include <hip/hip_runtime.h>
#include <cstdint>
#include <cstddef>

#define N_NODES 100000
#define DIM 512
#define NE 200000
#define NBLK 391   // ceil(N_NODES/256)

typedef __attribute__((ext_vector_type(4))) float floatx4;
typedef __attribute__((ext_vector_type(8))) short shortx8;

__device__ __forceinline__ unsigned short f2bf(float f) {
    union { float f; uint32_t u; } v; v.f = f;
    uint32_t r = v.u + 0x7fff + ((v.u >> 16) & 1);   // RNE
    return (unsigned short)(r >> 16);
}

__device__ __forceinline__ float bf2f(unsigned short h) {
    union { uint32_t u; float f; } v; v.u = ((uint32_t)h) << 16;
    return v.f;
}

__device__ __forceinline__ void load_lds16(const void* g, void* l) {
    __builtin_amdgcn_global_load_lds(
        (const __attribute__((address_space(1))) uint32_t*)g,
        (__attribute__((address_space(3))) uint32_t*)l, 16, 0, 0);
}

// ---------------- Wc = (W0+W1+W2)/3 -> bf16 ----------------
__global__ __launch_bounds__(256) void combine_w_kernel(
    const float* __restrict__ W0, const float* __restrict__ W1,
    const float* __restrict__ W2, unsigned short* __restrict__ Wc) {
    int i = blockIdx.x * 256 + threadIdx.x;   // exactly 512*512 threads
    Wc[i] = f2bf((W0[i] + W1[i] + W2[i]) * (1.0f / 3.0f));
}

// ---------------- x (fp32) -> xb (bf16), 8 elems/thread ----------------
__global__ __launch_bounds__(256) void convert_x_kernel(
    const float* __restrict__ x, unsigned short* __restrict__ xb) {
    size_t t = (size_t)blockIdx.x * 256 + threadIdx.x;   // 6.4M threads exactly
    const float4* xp = (const float4*)(x + t * 8);
    float4 v0 = xp[0];
    float4 v1 = xp[1];
    ushort4 o0, o1;
    o0.x = f2bf(v0.x); o0.y = f2bf(v0.y); o0.z = f2bf(v0.z); o0.w = f2bf(v0.w);
    o1.x = f2bf(v1.x); o1.y = f2bf(v1.y); o1.z = f2bf(v1.z); o1.w = f2bf(v1.w);
    ushort4* op = (ushort4*)(xb + t * 8);
    op[0] = o0;
    op[1] = o1;
}

// ---------------- per-etype in-degree counts ----------------
__global__ __launch_bounds__(256) void count_kernel(
    const int* __restrict__ d0, const int* __restrict__ d1,
    const int* __restrict__ d2, int* __restrict__ cnt) {
    int t = blockIdx.x * 256 + threadIdx.x;
    if (t >= 3 * NE) return;
    int e = t / NE;
    int i = t - e * NE;
    const int* dp = (e == 0) ? d0 : (e == 1) ? d1 : d2;
    atomicAdd(&cnt[e * N_NODES + dp[i]], 1);
}

// ---------------- scan pass 1: per-block sums of total row length ----------------
__global__ __launch_bounds__(256) void scan1_kernel(
    const int* __restrict__ cnt, int* __restrict__ bsum) {
    int t = threadIdx.x;
    int n = blockIdx.x * 256 + t;
    int rl = 0;
    if (n < N_NODES) rl = cnt[n] + cnt[N_NODES + n] + cnt[2 * N_NODES + n];
    int v = rl;
    #pragma unroll
    for (int off = 32; off > 0; off >>= 1) v += __shfl_xor(v, off);
    __shared__ int ws_[4];
    if ((t & 63) == 0) ws_[t >> 6] = v;
    __syncthreads();
    if (t == 0) bsum[blockIdx.x] = ws_[0] + ws_[1] + ws_[2] + ws_[3];
}

// ---------------- scan pass 2: exclusive scan of block sums (1 block) ----------------
__global__ __launch_bounds__(512) void scan2_kernel(
    const int* __restrict__ bsum, int* __restrict__ boff) {
    __shared__ int sh[512];
    int t = threadIdx.x;
    int v = (t < NBLK) ? bsum[t] : 0;
    sh[t] = v;
    __syncthreads();
    #pragma unroll
    for (int off = 1; off < 512; off <<= 1) {
        int add = (t >= off) ? sh[t - off] : 0;
        __syncthreads();
        sh[t] += add;
        __syncthreads();
    }
    if (t < NBLK) boff[t] = sh[t] - v;   // exclusive
}

// ---------------- scan pass 3: row_start + cursor ----------------
__global__ __launch_bounds__(256) void scan3_kernel(
    const int* __restrict__ cnt, const int* __restrict__ boff,
    int* __restrict__ row_start, int* __restrict__ cursor) {
    __shared__ int sh[256];
    int t = threadIdx.x;
    int n = blockIdx.x * 256 + t;
    int rl = 0;
    if (n < N_NODES) rl = cnt[n] + cnt[N_NODES + n] + cnt[2 * N_NODES + n];
    sh[t] = rl;
    __syncthreads();
    #pragma unroll
    for (int off = 1; off < 256; off <<= 1) {
        int add = (t >= off) ? sh[t - off] : 0;
        __syncthreads();
        sh[t] += add;
        __syncthreads();
    }
    if (n < N_NODES) {
        int excl = sh[t] - rl + boff[blockIdx.x];
        row_start[n] = excl;
        cursor[n] = excl;
    }
}

// ---------------- bin edges into CSR: src tagged with etype in bits 30-31 ----------------
__global__ __launch_bounds__(256) void bin_kernel(
    const int* __restrict__ s0, const int* __restrict__ d0,
    const int* __restrict__ s1, const int* __restrict__ d1,
    const int* __restrict__ s2, const int* __restrict__ d2,
    int* __restrict__ cursor, int* __restrict__ src_tag) {
    int t = blockIdx.x * 256 + threadIdx.x;
    if (t >= 3 * NE) return;
    int e = t / NE;
    int i = t - e * NE;
    const int* sp; const int* dp;
    if (e == 0)      { sp = s0; dp = d0; }
    else if (e == 1) { sp = s1; dp = d1; }
    else             { sp = s2; dp = d2; }
    int d = dp[i];
    int pos = atomicAdd(&cursor[d], 1);
    src_tag[pos] = sp[i] | (e << 30);
}

// ---------------- GEMM: H = xb @ Wc^T  (m97-style 128x128x32, bf16 out) ----------------
// Block: 256 threads = 4 waves in 2x2; each wave computes 64x64 via 4x4 16x16x32 frags.
// Grid: 782 M-tiles x 4 N-tiles = 3128 = 8*391 -> XCD-bijective swizzle for A-panel L2 reuse.
__global__ __launch_bounds__(256) void gemm_kernel(
    const unsigned short* __restrict__ A, const unsigned short* __restrict__ B,
    unsigned short* __restrict__ H, int M) {
    __shared__ alignas(16) unsigned short As[128 * 32];   // 8 KB
    __shared__ alignas(16) unsigned short Bs[128 * 32];   // 8 KB
    const int tid = threadIdx.x;
    const int lane = tid & 63;
    const int w = tid >> 6;            // 0..3
    const int wr = w >> 1, wc = w & 1; // wave grid 2x2
    const int q = lane >> 4, r = lane & 15;

    // XCD swizzle: HW maps final id f -> XCD f%8; logical id lid = (f%8)*391 + f/8
    // gives each XCD a contiguous run of 391 logical blocks (~98 M-tiles x 4 N-tiles).
    int lid = ((int)blockIdx.x & 7) * 391 + ((int)blockIdx.x >> 3);
    int mt = lid >> 2, nt = lid & 3;
    int m0 = mt * 128, n0 = nt * 128;

    floatx4 acc[4][4] = {};

    for (int k0 = 0; k0 < DIM; k0 += 32) {
        #pragma unroll
        for (int i = 0; i < 2; ++i) {
            int ca = i * 256 + tid;              // chunk 0..511 (16B chunks)
            int row = ca >> 2, c = ca & 3;
            int gm = m0 + row; if (gm >= M) gm = M - 1;     // clamp tail reads
            load_lds16(&A[(size_t)gm * DIM + k0 + c * 8], &As[ca * 8]);
            load_lds16(&B[(size_t)(n0 + row) * DIM + k0 + c * 8], &Bs[ca * 8]);
        }
        __syncthreads();
        shortx8 af[4], bfr[4];
        #pragma unroll
        for (int mi = 0; mi < 4; ++mi)
            af[mi] = *(const shortx8*)&As[(wr * 64 + mi * 16 + r) * 32 + q * 8];
        #pragma unroll
        for (int nj = 0; nj < 4; ++nj)
            bfr[nj] = *(const shortx8*)&Bs[(wc * 64 + nj * 16 + r) * 32 + q * 8];
        #pragma unroll
        for (int mi = 0; mi < 4; ++mi)
            #pragma unroll
            for (int nj = 0; nj < 4; ++nj)
                acc[mi][nj] = __builtin_amdgcn_mfma_f32_16x16x32_bf16(
                    af[mi], bfr[nj], acc[mi][nj], 0, 0, 0);
        __syncthreads();
    }

    // C/D layout (verified): col = r, row = q*4 + rg within each 16x16 frag
    #pragma unroll
    for (int mi = 0; mi < 4; ++mi) {
        #pragma unroll
        for (int rg = 0; rg < 4; ++rg) {
            int gm = m0 + wr * 64 + mi * 16 + q * 4 + rg;
            if (gm < M) {
                #pragma unroll
                for (int nj = 0; nj < 4; ++nj)
                    H[(size_t)gm * DIM + n0 + wc * 64 + nj * 16 + r] =
                        f2bf(acc[mi][nj][rg]);
            }
        }
    }
}

// ---------------- fused gather + ReLU + LayerNorm ----------------
// One wave per node; wave holds the full 512-dim row (lane*8..lane*8+8) in registers.
// Cooperative tag load: 64 tags per coalesced read, broadcast via __shfl.
__global__ __launch_bounds__(256) void gather_ln_kernel(
    const unsigned short* __restrict__ h, const int* __restrict__ row_start,
    const int* __restrict__ cnt, const int* __restrict__ src_tag,
    const float* __restrict__ gamma, const float* __restrict__ beta,
    float* __restrict__ out) {
    const int lane = threadIdx.x & 63;
    const int n = blockIdx.x * 4 + (threadIdx.x >> 6);
    if (n >= N_NODES) return;
    const int c0 = cnt[n], c1 = cnt[N_NODES + n], c2 = cnt[2 * N_NODES + n];
    const int len = c0 + c1 + c2;
    const float w0 = 1.0f / (3.0f * (float)max(c0, 1));
    const float w1 = 1.0f / (3.0f * (float)max(c1, 1));
    const float w2 = 1.0f / (3.0f * (float)max(c2, 1));
    const int beg = row_start[n];
    float acc[8] = {};
    for (int base = 0; base < len; base += 64) {
        int rem = len - base;
        int m = rem < 64 ? rem : 64;
        int tag = (lane < m) ? src_tag[beg + base + lane] : 0;
        for (int j = 0; j < m; ++j) {
            int u = __shfl(tag, j);
            int e = ((unsigned)u) >> 30;
            int s = u & 0x3FFFFFFF;
            float wgt = (e == 0) ? w0 : ((e == 1) ? w1 : w2);
            shortx8 v = *(const shortx8*)(h + (size_t)s * DIM + lane * 8);
            #pragma unroll
            for (int k = 0; k < 8; ++k)
                acc[k] += bf2f((unsigned short)v[k]) * wgt;
        }
    }
    // ReLU + row stats (fp32, exact over the wave's full row)
    float s1_ = 0.0f, s2_ = 0.0f;
    #pragma unroll
    for (int k = 0; k < 8; ++k) {
        float v = fmaxf(acc[k], 0.0f);
        acc[k] = v; s1_ += v; s2_ += v * v;
    }
    #pragma unroll
    for (int off = 1; off < 64; off <<= 1) {
        s1_ += __shfl_xor(s1_, off);
        s2_ += __shfl_xor(s2_, off);
    }
    float mu = s1_ * (1.0f / DIM);
    float var = s2_ * (1.0f / DIM) - mu * mu;
    float rstd = rsqrtf(var + 1e-5f);
    float4 g0 = *(const float4*)(gamma + lane * 8);
    float4 g1 = *(const float4*)(gamma + lane * 8 + 4);
    float4 b0 = *(const float4*)(beta + lane * 8);
    float4 b1 = *(const float4*)(beta + lane * 8 + 4);
    float4 o0, o1;
    o0.x = (acc[0] - mu) * rstd * g0.x + b0.x;
    o0.y = (acc[1] - mu) * rstd * g0.y + b0.y;
    o0.z = (acc[2] - mu) * rstd * g0.z + b0.z;
    o0.w = (acc[3] - mu) * rstd * g0.w + b0.w;
    o1.x = (acc[4] - mu) * rstd * g1.x + b1.x;
    o1.y = (acc[5] - mu) * rstd * g1.y + b1.y;
    o1.z = (acc[6] - mu) * rstd * g1.z + b1.z;
    o1.w = (acc[7] - mu) * rstd * g1.w + b1.w;
    float4* op = (float4*)(out + (size_t)n * DIM + lane * 8);
    op[0] = o0;
    op[1] = o1;
}

extern "C" void kernel_launch(void* const* d_in, const int* in_sizes, int n_in,
                              void* d_out, int out_size, void* d_ws, size_t ws_size,
                              hipStream_t stream) {
    const float* x     = (const float*)d_in[0];
    const float* W0    = (const float*)d_in[1];
    const float* W1    = (const float*)d_in[2];
    const float* W2    = (const float*)d_in[3];
    const float* gamma = (const float*)d_in[4];
    const float* beta  = (const float*)d_in[5];
    const int* s0  = (const int*)d_in[6];
    const int* dd0 = (const int*)d_in[7];
    const int* s1  = (const int*)d_in[8];
    const int* dd1 = (const int*)d_in[9];
    const int* s2  = (const int*)d_in[10];
    const int* dd2 = (const int*)d_in[11];
    float* out = (float*)d_out;

    // workspace layout (16B-aligned pieces)
    char* ws = (char*)d_ws;
    size_t off = 0;
    int* cnt = (int*)(ws + off);             off += 3u * N_NODES * 4u;          // 1.2 MB
    int* row_start = (int*)(ws + off);       off += (size_t)N_NODES * 4u;
    int* cursor = (int*)(ws + off);          off += (size_t)N_NODES * 4u;
    int* bsum = (int*)(ws + off);            off += 2048;
    int* boff = (int*)(ws + off);            off += 2048;
    int* src_tag = (int*)(ws + off);         off += (size_t)3 * NE * 4u;        // 2.4 MB
    unsigned short* Wc = (unsigned short*)(ws + off); off += (size_t)DIM * DIM * 2u;
    off = (off + 255) & ~255ull;
    unsigned short* xb = (unsigned short*)(ws + off); off += (size_t)N_NODES * DIM * 2u;  // 102.4 MB
    off = (off + 255) & ~255ull;
    unsigned short* h = (unsigned short*)(ws + off);                                      // 102.4 MB

    hipMemsetAsync(cnt, 0, (size_t)3 * N_NODES * sizeof(int), stream);

    combine_w_kernel<<<(DIM * DIM) / 256, 256, 0, stream>>>(W0, W1, W2, Wc);
    convert_x_kernel<<<(N_NODES * DIM / 8) / 256, 256, 0, stream>>>(x, xb);
    count_kernel<<<(3 * NE + 255) / 256, 256, 0, stream>>>(dd0, dd1, dd2, cnt);
    scan1_kernel<<<NBLK, 256, 0, stream>>>(cnt, bsum);
    scan2_kernel<<<1, 512, 0, stream>>>(bsum, boff);
    scan3_kernel<<<NBLK, 256, 0, stream>>>(cnt, boff, row_start, cursor);
    bin_kernel<<<(3 * NE + 255) / 256, 256, 0, stream>>>(
        s0, dd0, s1, dd1, s2, dd2, cursor, src_tag);

    // GEMM first: h = xb @ Wc^T  (bf16 out). 782 M-tiles x 4 N-tiles = 3128 blocks.
    gemm_kernel<<<3128, 256, 0, stream>>>(xb, Wc, h, N_NODES);

    // Fused aggregate + ReLU + LayerNorm (fp32 accumulate, full row per wave).
    gather_ln_kernel<<<(N_NODES + 3) / 4, 256, 0, stream>>>(
        h, row_start, cnt, src_tag, gamma, beta, out);
}

// Round 2
// 575.662 us; speedup vs baseline: 1.2782x; 1.0783x over previous
//
#include <hip/hip_runtime.h>
#include <cstdint>
#include <cstddef>

#define N_NODES 100000
#define DIM 512
#define NE 200000
#define NBLK 391   // ceil(N_NODES/256)

typedef __attribute__((ext_vector_type(4))) float floatx4;
typedef __attribute__((ext_vector_type(8))) short shortx8;

__device__ __forceinline__ unsigned short f2bf(float f) {
    union { float f; uint32_t u; } v; v.f = f;
    uint32_t r = v.u + 0x7fff + ((v.u >> 16) & 1);   // RNE
    return (unsigned short)(r >> 16);
}

__device__ __forceinline__ float bf2f(unsigned short h) {
    union { uint32_t u; float f; } v; v.u = ((uint32_t)h) << 16;
    return v.f;
}

__device__ __forceinline__ void load_lds16(const void* g, void* l) {
    __builtin_amdgcn_global_load_lds(
        (const __attribute__((address_space(1))) uint32_t*)g,
        (__attribute__((address_space(3))) uint32_t*)l, 16, 0, 0);
}

// ---------------- Wc = (W0+W1+W2)/3 -> bf16 ----------------
__global__ __launch_bounds__(256) void combine_w_kernel(
    const float* __restrict__ W0, const float* __restrict__ W1,
    const float* __restrict__ W2, unsigned short* __restrict__ Wc) {
    int i = blockIdx.x * 256 + threadIdx.x;   // exactly 512*512 threads
    Wc[i] = f2bf((W0[i] + W1[i] + W2[i]) * (1.0f / 3.0f));
}

// ---------------- per-etype in-degree counts ----------------
__global__ __launch_bounds__(256) void count_kernel(
    const int* __restrict__ d0, const int* __restrict__ d1,
    const int* __restrict__ d2, int* __restrict__ cnt) {
    int t = blockIdx.x * 256 + threadIdx.x;
    if (t >= 3 * NE) return;
    int e = t / NE;
    int i = t - e * NE;
    const int* dp = (e == 0) ? d0 : (e == 1) ? d1 : d2;
    atomicAdd(&cnt[e * N_NODES + dp[i]], 1);
}

// ---------------- scan pass 1: per-block sums of total row length ----------------
__global__ __launch_bounds__(256) void scan1_kernel(
    const int* __restrict__ cnt, int* __restrict__ bsum) {
    int t = threadIdx.x;
    int n = blockIdx.x * 256 + t;
    int rl = 0;
    if (n < N_NODES) rl = cnt[n] + cnt[N_NODES + n] + cnt[2 * N_NODES + n];
    int v = rl;
    #pragma unroll
    for (int off = 32; off > 0; off >>= 1) v += __shfl_xor(v, off);
    __shared__ int ws_[4];
    if ((t & 63) == 0) ws_[t >> 6] = v;
    __syncthreads();
    if (t == 0) bsum[blockIdx.x] = ws_[0] + ws_[1] + ws_[2] + ws_[3];
}

// ---------------- scan pass 2: exclusive scan of block sums (1 block) ----------------
__global__ __launch_bounds__(512) void scan2_kernel(
    const int* __restrict__ bsum, int* __restrict__ boff) {
    __shared__ int sh[512];
    int t = threadIdx.x;
    int v = (t < NBLK) ? bsum[t] : 0;
    sh[t] = v;
    __syncthreads();
    #pragma unroll
    for (int off = 1; off < 512; off <<= 1) {
        int add = (t >= off) ? sh[t - off] : 0;
        __syncthreads();
        sh[t] += add;
        __syncthreads();
    }
    if (t < NBLK) boff[t] = sh[t] - v;   // exclusive
}

// ---------------- scan pass 3: row_start + cursor ----------------
__global__ __launch_bounds__(256) void scan3_kernel(
    const int* __restrict__ cnt, const int* __restrict__ boff,
    int* __restrict__ row_start, int* __restrict__ cursor) {
    __shared__ int sh[256];
    int t = threadIdx.x;
    int n = blockIdx.x * 256 + t;
    int rl = 0;
    if (n < N_NODES) rl = cnt[n] + cnt[N_NODES + n] + cnt[2 * N_NODES + n];
    sh[t] = rl;
    __syncthreads();
    #pragma unroll
    for (int off = 1; off < 256; off <<= 1) {
        int add = (t >= off) ? sh[t - off] : 0;
        __syncthreads();
        sh[t] += add;
        __syncthreads();
    }
    if (n < N_NODES) {
        int excl = sh[t] - rl + boff[blockIdx.x];
        row_start[n] = excl;
        cursor[n] = excl;
    }
}

// ---------------- bin edges into CSR: src tagged with etype in bits 30-31 ----------------
__global__ __launch_bounds__(256) void bin_kernel(
    const int* __restrict__ s0, const int* __restrict__ d0,
    const int* __restrict__ s1, const int* __restrict__ d1,
    const int* __restrict__ s2, const int* __restrict__ d2,
    int* __restrict__ cursor, int* __restrict__ src_tag) {
    int t = blockIdx.x * 256 + threadIdx.x;
    if (t >= 3 * NE) return;
    int e = t / NE;
    int i = t - e * NE;
    const int* sp; const int* dp;
    if (e == 0)      { sp = s0; dp = d0; }
    else if (e == 1) { sp = s1; dp = d1; }
    else             { sp = s2; dp = d2; }
    int d = dp[i];
    int pos = atomicAdd(&cursor[d], 1);
    src_tag[pos] = sp[i] | (e << 30);
}

// ---------------- GEMM: H = bf16(X) @ Wc^T, fused fp32->bf16 convert on A ----------------
// Block: 256 threads = 4 waves in 2x2; each wave computes 64x64 via 4x4 16x16x32 frags.
// A staged via reg (global fp32 -> cvt bf16 -> ds_write_b128), B via global_load_lds.
// Grid: 782 M-tiles x 4 N-tiles = 3128 = 8*391 -> XCD-bijective swizzle so the 4
// N-tile siblings of an A-panel share one XCD's L2 (fp32 A fetched from HBM once).
__global__ __launch_bounds__(256) void gemm_kernel(
    const float* __restrict__ X, const unsigned short* __restrict__ B,
    unsigned short* __restrict__ H, int M) {
    __shared__ alignas(16) unsigned short As[128 * 32];   // 8 KB
    __shared__ alignas(16) unsigned short Bs[128 * 32];   // 8 KB
    const int tid = threadIdx.x;
    const int lane = tid & 63;
    const int w = tid >> 6;            // 0..3
    const int wr = w >> 1, wc = w & 1; // wave grid 2x2
    const int q = lane >> 4, r = lane & 15;

    int lid = ((int)blockIdx.x & 7) * 391 + ((int)blockIdx.x >> 3);
    int mt = lid >> 2, nt = lid & 3;
    int m0 = mt * 128, n0 = nt * 128;

    // A-staging: chunk ca in [0,512): row = ca>>2, col8 = ca&3. Thread t owns ca = t, t+256.
    int arow0 = tid >> 2, ac8 = tid & 3;
    int gm0 = m0 + arow0;       if (gm0 >= M) gm0 = M - 1;
    int gm1 = m0 + arow0 + 64;  if (gm1 >= M) gm1 = M - 1;
    const float* ap0 = X + (size_t)gm0 * DIM + ac8 * 8;
    const float* ap1 = X + (size_t)gm1 * DIM + ac8 * 8;

    float4 a00, a01, a10, a11;   // two chunks x 8 floats
    #define ALOAD(k0_) do { \
        a00 = *(const float4*)(ap0 + (k0_));     a01 = *(const float4*)(ap0 + (k0_) + 4); \
        a10 = *(const float4*)(ap1 + (k0_));     a11 = *(const float4*)(ap1 + (k0_) + 4); \
    } while (0)

    floatx4 acc[4][4] = {};
    ALOAD(0);

    for (int k0 = 0; k0 < DIM; k0 += 32) {
        // stage B (bf16) via direct-to-LDS
        #pragma unroll
        for (int i = 0; i < 2; ++i) {
            int cb = i * 256 + tid;
            int row = cb >> 2, c = cb & 3;
            load_lds16(&B[(size_t)(n0 + row) * DIM + k0 + c * 8], &Bs[cb * 8]);
        }
        // stage A: cvt fp32 regs -> bf16, ds_write_b128 (compiler waits A-vmcnt only)
        {
            shortx8 p0, p1;
            p0[0] = f2bf(a00.x); p0[1] = f2bf(a00.y); p0[2] = f2bf(a00.z); p0[3] = f2bf(a00.w);
            p0[4] = f2bf(a01.x); p0[5] = f2bf(a01.y); p0[6] = f2bf(a01.z); p0[7] = f2bf(a01.w);
            p1[0] = f2bf(a10.x); p1[1] = f2bf(a10.y); p1[2] = f2bf(a10.z); p1[3] = f2bf(a10.w);
            p1[4] = f2bf(a11.x); p1[5] = f2bf(a11.y); p1[6] = f2bf(a11.z); p1[7] = f2bf(a11.w);
            *(shortx8*)&As[tid * 8] = p0;
            *(shortx8*)&As[(tid + 256) * 8] = p1;
        }
        __syncthreads();
        // prefetch next A K-step (overlaps ds_read + MFMA below)
        if (k0 + 32 < DIM) ALOAD(k0 + 32);

        shortx8 af[4], bfr[4];
        #pragma unroll
        for (int mi = 0; mi < 4; ++mi)
            af[mi] = *(const shortx8*)&As[(wr * 64 + mi * 16 + r) * 32 + q * 8];
        #pragma unroll
        for (int nj = 0; nj < 4; ++nj)
            bfr[nj] = *(const shortx8*)&Bs[(wc * 64 + nj * 16 + r) * 32 + q * 8];
        #pragma unroll
        for (int mi = 0; mi < 4; ++mi)
            #pragma unroll
            for (int nj = 0; nj < 4; ++nj)
                acc[mi][nj] = __builtin_amdgcn_mfma_f32_16x16x32_bf16(
                    af[mi], bfr[nj], acc[mi][nj], 0, 0, 0);
        __syncthreads();
    }
    #undef ALOAD

    // C/D layout: col = r, row = q*4 + rg within each 16x16 frag
    #pragma unroll
    for (int mi = 0; mi < 4; ++mi) {
        #pragma unroll
        for (int rg = 0; rg < 4; ++rg) {
            int gm = m0 + wr * 64 + mi * 16 + q * 4 + rg;
            if (gm < M) {
                #pragma unroll
                for (int nj = 0; nj < 4; ++nj)
                    H[(size_t)gm * DIM + n0 + wc * 64 + nj * 16 + r] =
                        f2bf(acc[mi][nj][rg]);
            }
        }
    }
}

// ---------------- fused gather + ReLU + LayerNorm ----------------
// One wave per node; wave holds the full 512-dim row (lane*8..lane*8+8) in registers.
// Cooperative tag load (64/batch) + 4-wide unrolled edge loop for memory-level parallelism.
__global__ __launch_bounds__(256) void gather_ln_kernel(
    const unsigned short* __restrict__ h, const int* __restrict__ row_start,
    const int* __restrict__ cnt, const int* __restrict__ src_tag,
    const float* __restrict__ gamma, const float* __restrict__ beta,
    float* __restrict__ out) {
    const int lane = threadIdx.x & 63;
    const int n = blockIdx.x * 4 + (threadIdx.x >> 6);
    if (n >= N_NODES) return;
    const int c0 = cnt[n], c1 = cnt[N_NODES + n], c2 = cnt[2 * N_NODES + n];
    const int len = c0 + c1 + c2;
    const float w0 = 1.0f / (3.0f * (float)max(c0, 1));
    const float w1 = 1.0f / (3.0f * (float)max(c1, 1));
    const float w2 = 1.0f / (3.0f * (float)max(c2, 1));
    const int beg = row_start[n];
    const size_t lx = (size_t)lane * 8;
    float acc[8] = {};
    for (int base = 0; base < len; base += 64) {
        int rem = len - base;
        int m = rem < 64 ? rem : 64;
        int tag = (lane < m) ? src_tag[beg + base + lane] : 0;
        int j = 0;
        for (; j + 4 <= m; j += 4) {
            int u0 = __shfl(tag, j),     u1 = __shfl(tag, j + 1);
            int u2 = __shfl(tag, j + 2), u3 = __shfl(tag, j + 3);
            int e0 = ((unsigned)u0) >> 30, e1 = ((unsigned)u1) >> 30;
            int e2 = ((unsigned)u2) >> 30, e3 = ((unsigned)u3) >> 30;
            float g0 = (e0 == 0) ? w0 : ((e0 == 1) ? w1 : w2);
            float g1 = (e1 == 0) ? w0 : ((e1 == 1) ? w1 : w2);
            float g2 = (e2 == 0) ? w0 : ((e2 == 1) ? w1 : w2);
            float g3 = (e3 == 0) ? w0 : ((e3 == 1) ? w1 : w2);
            shortx8 v0 = *(const shortx8*)(h + (size_t)(u0 & 0x3FFFFFFF) * DIM + lx);
            shortx8 v1 = *(const shortx8*)(h + (size_t)(u1 & 0x3FFFFFFF) * DIM + lx);
            shortx8 v2 = *(const shortx8*)(h + (size_t)(u2 & 0x3FFFFFFF) * DIM + lx);
            shortx8 v3 = *(const shortx8*)(h + (size_t)(u3 & 0x3FFFFFFF) * DIM + lx);
            #pragma unroll
            for (int k = 0; k < 8; ++k) {
                acc[k] += bf2f((unsigned short)v0[k]) * g0;
                acc[k] += bf2f((unsigned short)v1[k]) * g1;
                acc[k] += bf2f((unsigned short)v2[k]) * g2;
                acc[k] += bf2f((unsigned short)v3[k]) * g3;
            }
        }
        for (; j < m; ++j) {
            int u = __shfl(tag, j);
            int e = ((unsigned)u) >> 30;
            float wg = (e == 0) ? w0 : ((e == 1) ? w1 : w2);
            shortx8 v = *(const shortx8*)(h + (size_t)(u & 0x3FFFFFFF) * DIM + lx);
            #pragma unroll
            for (int k = 0; k < 8; ++k)
                acc[k] += bf2f((unsigned short)v[k]) * wg;
        }
    }
    // ReLU + row stats (fp32, exact over the wave's full row)
    float s1_ = 0.0f, s2_ = 0.0f;
    #pragma unroll
    for (int k = 0; k < 8; ++k) {
        float v = fmaxf(acc[k], 0.0f);
        acc[k] = v; s1_ += v; s2_ += v * v;
    }
    #pragma unroll
    for (int off = 1; off < 64; off <<= 1) {
        s1_ += __shfl_xor(s1_, off);
        s2_ += __shfl_xor(s2_, off);
    }
    float mu = s1_ * (1.0f / DIM);
    float var = s2_ * (1.0f / DIM) - mu * mu;
    float rstd = rsqrtf(var + 1e-5f);
    float4 g0 = *(const float4*)(gamma + lane * 8);
    float4 g1 = *(const float4*)(gamma + lane * 8 + 4);
    float4 b0 = *(const float4*)(beta + lane * 8);
    float4 b1 = *(const float4*)(beta + lane * 8 + 4);
    float4 o0, o1;
    o0.x = (acc[0] - mu) * rstd * g0.x + b0.x;
    o0.y = (acc[1] - mu) * rstd * g0.y + b0.y;
    o0.z = (acc[2] - mu) * rstd * g0.z + b0.z;
    o0.w = (acc[3] - mu) * rstd * g0.w + b0.w;
    o1.x = (acc[4] - mu) * rstd * g1.x + b1.x;
    o1.y = (acc[5] - mu) * rstd * g1.y + b1.y;
    o1.z = (acc[6] - mu) * rstd * g1.z + b1.z;
    o1.w = (acc[7] - mu) * rstd * g1.w + b1.w;
    float4* op = (float4*)(out + (size_t)n * DIM + lane * 8);
    op[0] = o0;
    op[1] = o1;
}

extern "C" void kernel_launch(void* const* d_in, const int* in_sizes, int n_in,
                              void* d_out, int out_size, void* d_ws, size_t ws_size,
                              hipStream_t stream) {
    const float* x     = (const float*)d_in[0];
    const float* W0    = (const float*)d_in[1];
    const float* W1    = (const float*)d_in[2];
    const float* W2    = (const float*)d_in[3];
    const float* gamma = (const float*)d_in[4];
    const float* beta  = (const float*)d_in[5];
    const int* s0  = (const int*)d_in[6];
    const int* dd0 = (const int*)d_in[7];
    const int* s1  = (const int*)d_in[8];
    const int* dd1 = (const int*)d_in[9];
    const int* s2  = (const int*)d_in[10];
    const int* dd2 = (const int*)d_in[11];
    float* out = (float*)d_out;

    // workspace layout (16B-aligned pieces)
    char* ws = (char*)d_ws;
    size_t off = 0;
    int* cnt = (int*)(ws + off);             off += 3u * N_NODES * 4u;          // 1.2 MB
    int* row_start = (int*)(ws + off);       off += (size_t)N_NODES * 4u;
    int* cursor = (int*)(ws + off);          off += (size_t)N_NODES * 4u;
    int* bsum = (int*)(ws + off);            off += 2048;
    int* boff = (int*)(ws + off);            off += 2048;
    int* src_tag = (int*)(ws + off);         off += (size_t)3 * NE * 4u;        // 2.4 MB
    unsigned short* Wc = (unsigned short*)(ws + off); off += (size_t)DIM * DIM * 2u;
    off = (off + 255) & ~255ull;
    unsigned short* h = (unsigned short*)(ws + off);                            // 102.4 MB

    hipMemsetAsync(cnt, 0, (size_t)3 * N_NODES * sizeof(int), stream);

    combine_w_kernel<<<(DIM * DIM) / 256, 256, 0, stream>>>(W0, W1, W2, Wc);
    count_kernel<<<(3 * NE + 255) / 256, 256, 0, stream>>>(dd0, dd1, dd2, cnt);
    scan1_kernel<<<NBLK, 256, 0, stream>>>(cnt, bsum);
    scan2_kernel<<<1, 512, 0, stream>>>(bsum, boff);
    scan3_kernel<<<NBLK, 256, 0, stream>>>(cnt, boff, row_start, cursor);
    bin_kernel<<<(3 * NE + 255) / 256, 256, 0, stream>>>(
        s0, dd0, s1, dd1, s2, dd2, cursor, src_tag);

    // GEMM with fused fp32->bf16 convert on A: h = bf16(x) @ Wc^T (bf16 out).
    gemm_kernel<<<3128, 256, 0, stream>>>(x, Wc, h, N_NODES);

    // Fused aggregate + ReLU + LayerNorm (fp32 accumulate, full row per wave).
    gather_ln_kernel<<<(N_NODES + 3) / 4, 256, 0, stream>>>(
        h, row_start, cnt, src_tag, gamma, beta, out);
}